// Round 1
// baseline (124.106 us; speedup 1.0000x reference)
//
#include <hip/hip_runtime.h>

// B=8, S=4096, E=256, H=4, DK=64. Tokens = B*S = 32768.
// Round-4: M=64 tokens/block, 512 threads (8 waves), wave owns 64 rows x 32 cols
// (acc[4][2]). Every packed-weight fragment is loaded exactly once per block
// (halves weight traffic vs M=32), MFMA:global-load ratio 8:2 per kk-step,
// grid 512 = exactly 2 zero-tail rounds at 1 block/CU.
// LDS 105.4 KB (3 x 64-row bf16 buffers + PL), __launch_bounds__(512,2).

typedef __bf16 bf16x8 __attribute__((ext_vector_type(8)));
typedef __bf16 bf16x4 __attribute__((ext_vector_type(4)));
typedef float f32x4 __attribute__((ext_vector_type(4)));

#define LDW 264   // LDS row stride in bf16 elems (256+8 pad; rows stay 16B-aligned)
#define MROWS 64  // tokens per block

// ---------- prep: pack W into fragment-contiguous bf16 (UNCHANGED layout) ----------
// Fragment (p, g16, kk): lane(lh=lane&15, lq=lane>>4) holds
//   W_p[g16*16 + lh][kk*32 + lq*8 + j], j=0..7  (8 bf16 = 16B)
// stored at Wpk[frag_id*512 + lane*8], frag_id = p*128 + g16*8 + kk, g16 = 0..15.
__global__ void pack_wfrag(const float* __restrict__ Wq, const float* __restrict__ Wk,
                           const float* __restrict__ Wv, const float* __restrict__ Wo,
                           __bf16* __restrict__ Wpk) {
  const int f    = blockIdx.x;          // 0..511
  const int lane = threadIdx.x;         // 0..63
  const int kk  = f & 7;
  const int g16 = (f >> 3) & 15;
  const int p   = f >> 7;
  const float* W = (p == 0) ? Wq : (p == 1) ? Wk : (p == 2) ? Wv : Wo;
  const int lh = lane & 15, lq = lane >> 4;
  const int n  = g16 * 16 + lh;
  const int k0 = kk * 32 + lq * 8;
  const float4 s0 = *(const float4*)&W[n * 256 + k0];
  const float4 s1 = *(const float4*)&W[n * 256 + k0 + 4];
  bf16x8 r;
  r[0] = (__bf16)s0.x; r[1] = (__bf16)s0.y; r[2] = (__bf16)s0.z; r[3] = (__bf16)s0.w;
  r[4] = (__bf16)s1.x; r[5] = (__bf16)s1.y; r[6] = (__bf16)s1.z; r[7] = (__bf16)s1.w;
  *(bf16x8*)&Wpk[(size_t)f * 512 + lane * 8] = r;
}

// ---------- fused attention ----------
// One 64x32 projection slice per wave; A-frags from LDS, B-frags from packed global.
// wbase points at frag (p, g16=2w, kk=0); loads at + (nf*8+kk)*512 + lane*8, nf=0..1.
__device__ __forceinline__ void proj64(const __bf16* __restrict__ xs_,
                                       const __bf16* __restrict__ wbase,
                                       int lh, int lq, int lane, f32x4 acc[4][2]) {
  const __bf16* ap = xs_ + lh * LDW + lq * 8;
  const __bf16* wl = wbase + lane * 8;
  #pragma unroll
  for (int kk = 0; kk < 8; ++kk) {
    bf16x8 a0 = *(const bf16x8*)(ap +  0 * LDW + kk * 32);
    bf16x8 a1 = *(const bf16x8*)(ap + 16 * LDW + kk * 32);
    bf16x8 a2 = *(const bf16x8*)(ap + 32 * LDW + kk * 32);
    bf16x8 a3 = *(const bf16x8*)(ap + 48 * LDW + kk * 32);
    bf16x8 w0 = *(const bf16x8*)(wl + (0 * 8 + kk) * 512);
    bf16x8 w1 = *(const bf16x8*)(wl + (1 * 8 + kk) * 512);
    acc[0][0] = __builtin_amdgcn_mfma_f32_16x16x32_bf16(a0, w0, acc[0][0], 0, 0, 0);
    acc[1][0] = __builtin_amdgcn_mfma_f32_16x16x32_bf16(a1, w0, acc[1][0], 0, 0, 0);
    acc[2][0] = __builtin_amdgcn_mfma_f32_16x16x32_bf16(a2, w0, acc[2][0], 0, 0, 0);
    acc[3][0] = __builtin_amdgcn_mfma_f32_16x16x32_bf16(a3, w0, acc[3][0], 0, 0, 0);
    acc[0][1] = __builtin_amdgcn_mfma_f32_16x16x32_bf16(a0, w1, acc[0][1], 0, 0, 0);
    acc[1][1] = __builtin_amdgcn_mfma_f32_16x16x32_bf16(a1, w1, acc[1][1], 0, 0, 0);
    acc[2][1] = __builtin_amdgcn_mfma_f32_16x16x32_bf16(a2, w1, acc[2][1], 0, 0, 0);
    acc[3][1] = __builtin_amdgcn_mfma_f32_16x16x32_bf16(a3, w1, acc[3][1], 0, 0, 0);
  }
}

__device__ __forceinline__ void store_cd64(__bf16* __restrict__ buf, const f32x4 acc[4][2],
                                           const float* __restrict__ bias,
                                           int n0, int lh, int lq) {
  #pragma unroll
  for (int nf = 0; nf < 2; ++nf) {
    int col = n0 + nf * 16 + lh;
    float bb = bias[col];
    #pragma unroll
    for (int mf = 0; mf < 4; ++mf) {
      int r = mf * 16 + lq * 4;
      #pragma unroll
      for (int j = 0; j < 4; ++j)
        buf[(r + j) * LDW + col] = (__bf16)(acc[mf][nf][j] + bb);
    }
  }
}

__launch_bounds__(512, 2)
__global__ void fused_attn(const float* __restrict__ x, const __bf16* __restrict__ Wpk,
                           const float* __restrict__ bq, const float* __restrict__ bk,
                           const float* __restrict__ bv, const float* __restrict__ bo,
                           float* __restrict__ out) {
  __shared__ __bf16 xs[MROWS * LDW];    // x tile (live through V projection)
  __shared__ __bf16 qs[MROWS * LDW];    // Q, then V
  __shared__ __bf16 ksh[MROWS * LDW];   // K, then Y
  __shared__ float PL[MROWS * 16];

  const int tid  = threadIdx.x;          // 0..511
  const int lane = tid & 63;
  const int w    = tid >> 6;             // wave 0..7
  const int lh   = lane & 15;
  const int lq   = lane >> 4;
  const int n0   = w * 32;
  const int tok0 = blockIdx.x * MROWS;

  // ---- stage x tile: lane-contiguous float4 loads -> bf16 padded LDS ----
  const float4* xg = (const float4*)(x + (size_t)tok0 * 256);
  #pragma unroll
  for (int i = 0; i < 8; ++i) {
    int idx = i * 512 + tid;           // float4 id, 0..4095
    int row = idx >> 6;                // 64 float4 per row
    int c4  = idx & 63;
    float4 v = xg[idx];
    bf16x4 pk;
    pk[0] = (__bf16)v.x; pk[1] = (__bf16)v.y; pk[2] = (__bf16)v.z; pk[3] = (__bf16)v.w;
    *(bf16x4*)&xs[row * LDW + c4 * 4] = pk;
  }
  __syncthreads();

  // per-(proj,wave) packed-weight base: frag_id = p*128 + (2w+nf)*8 + kk
  const __bf16* wqb = Wpk + (size_t)(0 * 128 + w * 16) * 512;
  const __bf16* wkb = Wpk + (size_t)(1 * 128 + w * 16) * 512;
  const __bf16* wvb = Wpk + (size_t)(2 * 128 + w * 16) * 512;
  const __bf16* wob = Wpk + (size_t)(3 * 128 + w * 16) * 512;

  // ---- Q projection ----
  {
    f32x4 acc[4][2];
    #pragma unroll
    for (int mf = 0; mf < 4; ++mf)
      #pragma unroll
      for (int nf = 0; nf < 2; ++nf) acc[mf][nf] = (f32x4){0.f, 0.f, 0.f, 0.f};
    proj64(xs, wqb, lh, lq, lane, acc);
    store_cd64(qs, acc, bq, n0, lh, lq);
  }
  // ---- K projection ----
  {
    f32x4 acc[4][2];
    #pragma unroll
    for (int mf = 0; mf < 4; ++mf)
      #pragma unroll
      for (int nf = 0; nf < 2; ++nf) acc[mf][nf] = (f32x4){0.f, 0.f, 0.f, 0.f};
    proj64(xs, wkb, lh, lq, lane, acc);
    store_cd64(ksh, acc, bk, n0, lh, lq);
  }
  __syncthreads();   // Q,K visible

  // ---- scores + softmax: 4 active threads per token (512 thr -> 64 tokens) ----
  {
    const int m   = tid >> 3;            // 0..63
    const int sub = tid & 7;
    if (sub < 4) {
      const int h = sub;
      float d0 = 0.f, d1 = 0.f, d2 = 0.f, d3 = 0.f;
      #pragma unroll
      for (int i = 0; i < 8; ++i) {
        bf16x8 qv = *(const bf16x8*)&qs[m * LDW + h * 64 + i * 8];
        bf16x8 k0 = *(const bf16x8*)&ksh[m * LDW +   0 + i * 8];
        bf16x8 k1 = *(const bf16x8*)&ksh[m * LDW +  64 + i * 8];
        bf16x8 k2 = *(const bf16x8*)&ksh[m * LDW + 128 + i * 8];
        bf16x8 k3 = *(const bf16x8*)&ksh[m * LDW + 192 + i * 8];
        #pragma unroll
        for (int j = 0; j < 8; ++j) {
          float qf = (float)qv[j];
          d0 += qf * (float)k0[j];
          d1 += qf * (float)k1[j];
          d2 += qf * (float)k2[j];
          d3 += qf * (float)k3[j];
        }
      }
      d0 *= 0.125f; d1 *= 0.125f; d2 *= 0.125f; d3 *= 0.125f;  // 1/sqrt(64)
      float mx = fmaxf(fmaxf(d0, d1), fmaxf(d2, d3));
      float e0 = expf(d0 - mx), e1 = expf(d1 - mx), e2 = expf(d2 - mx), e3 = expf(d3 - mx);
      float inv = 1.0f / (e0 + e1 + e2 + e3);
      float* pl = &PL[m * 16 + h * 4];
      pl[0] = e0 * inv; pl[1] = e1 * inv; pl[2] = e2 * inv; pl[3] = e3 * inv;
    }
  }
  __syncthreads();   // P visible; Q,K reads complete

  // ---- V projection (overwrites Q region) ----
  {
    f32x4 acc[4][2];
    #pragma unroll
    for (int mf = 0; mf < 4; ++mf)
      #pragma unroll
      for (int nf = 0; nf < 2; ++nf) acc[mf][nf] = (f32x4){0.f, 0.f, 0.f, 0.f};
    proj64(xs, wvb, lh, lq, lane, acc);
    store_cd64(qs, acc, bv, n0, lh, lq);
  }
  __syncthreads();   // V visible

  // ---- y-mix: y[m, h*64+d] = sum_g P[h][g] * v[m, g*64+d]; Y -> ksh ----
  {
    const int m   = tid >> 3;            // 0..63
    const int sub = tid & 7;
    const int h   = sub >> 1;
    const int c0  = (sub & 1) * 32;
    const float p0 = PL[m * 16 + h * 4 + 0];
    const float p1 = PL[m * 16 + h * 4 + 1];
    const float p2 = PL[m * 16 + h * 4 + 2];
    const float p3 = PL[m * 16 + h * 4 + 3];
    #pragma unroll
    for (int dd = 0; dd < 32; dd += 8) {
      int c = c0 + dd;
      bf16x8 v0 = *(const bf16x8*)&qs[m * LDW +   0 + c];
      bf16x8 v1 = *(const bf16x8*)&qs[m * LDW +  64 + c];
      bf16x8 v2 = *(const bf16x8*)&qs[m * LDW + 128 + c];
      bf16x8 v3 = *(const bf16x8*)&qs[m * LDW + 192 + c];
      bf16x8 yv;
      #pragma unroll
      for (int j = 0; j < 8; ++j) {
        float f = p0 * (float)v0[j] + p1 * (float)v1[j]
                + p2 * (float)v2[j] + p3 * (float)v3[j];
        yv[j] = (__bf16)f;
      }
      *(bf16x8*)&ksh[m * LDW + h * 64 + c] = yv;
    }
  }
  __syncthreads();   // Y visible

  // ---- output GEMM: out = Y @ Wo^T + bo (A from LDS Y in ksh) ----
  {
    f32x4 acc[4][2];
    #pragma unroll
    for (int mf = 0; mf < 4; ++mf)
      #pragma unroll
      for (int nf = 0; nf < 2; ++nf) acc[mf][nf] = (f32x4){0.f, 0.f, 0.f, 0.f};
    proj64(ksh, wob, lh, lq, lane, acc);

    #pragma unroll
    for (int nf = 0; nf < 2; ++nf) {
      int col = n0 + nf * 16 + lh;
      float bb = bo[col];
      #pragma unroll
      for (int mf = 0; mf < 4; ++mf) {
        int rbase = tok0 + mf * 16 + lq * 4;
        #pragma unroll
        for (int j = 0; j < 4; ++j)
          out[(size_t)(rbase + j) * 256 + col] = acc[mf][nf][j] + bb;
      }
    }
  }
}

extern "C" void kernel_launch(void* const* d_in, const int* in_sizes, int n_in,
                              void* d_out, int out_size, void* d_ws, size_t ws_size,
                              hipStream_t stream) {
  const float* x  = (const float*)d_in[0];
  const float* Wq = (const float*)d_in[1];
  const float* bq = (const float*)d_in[2];
  const float* Wk = (const float*)d_in[3];
  const float* bk = (const float*)d_in[4];
  const float* Wv = (const float*)d_in[5];
  const float* bv = (const float*)d_in[6];
  const float* Wo = (const float*)d_in[7];
  const float* bo = (const float*)d_in[8];
  float* out = (float*)d_out;
  __bf16* Wpk = (__bf16*)d_ws;   // 512 frags x 1KB = 512 KB

  pack_wfrag<<<dim3(512), dim3(64), 0, stream>>>(Wq, Wk, Wv, Wo, Wpk);
  fused_attn<<<dim3(512), dim3(512), 0, stream>>>(x, Wpk, bq, bk, bv, bo, out);
}

// Round 3
// 120.781 us; speedup vs baseline: 1.0275x; 1.0275x over previous
//
#include <hip/hip_runtime.h>

// B=8, S=4096, E=256, H=4, DK=64. Tokens = B*S = 32768.
// Round-5 (resubmit; lease timeout last round, never measured).
// Schedule fix on the round-4 structure (M=64, 512 thr, 8 waves,
// wave = 64 rows x 32 cols). Counters showed 1 block/CU (LDS 103KB), 2 waves/SIMD,
// MfmaUtil 15% / VALU 24% / HBM 17% -> latency-exposed, not BW-bound.
//  - W-frags for a proj are PRELOADED into registers (16 x bf16x8) before
//    the MFMA loop; Q+K both loaded upfront, V preloaded under the softmax
//    barrier, O preloaded under the ymix barrier. Proj loop = pure LDS+MFMA.
//  - Softmax wave-parallelized: 8 threads/token (d-range split), shfl_xor(4)
//    combine -> all 64 lanes active, serial LDS chain halved.

typedef __bf16 bf16x8 __attribute__((ext_vector_type(8)));
typedef __bf16 bf16x4 __attribute__((ext_vector_type(4)));
typedef float f32x4 __attribute__((ext_vector_type(4)));

#define LDW 264   // LDS row stride in bf16 elems (256+8 pad; rows stay 16B-aligned)
#define MROWS 64  // tokens per block

// ---------- prep: pack W into fragment-contiguous bf16 (layout unchanged) ----------
// Fragment (p, g16, kk): lane(lh=lane&15, lq=lane>>4) holds
//   W_p[g16*16 + lh][kk*32 + lq*8 + j], j=0..7  (8 bf16 = 16B)
// stored at Wpk[frag_id*512 + lane*8], frag_id = p*128 + g16*8 + kk, g16 = 0..15.
__global__ void pack_wfrag(const float* __restrict__ Wq, const float* __restrict__ Wk,
                           const float* __restrict__ Wv, const float* __restrict__ Wo,
                           __bf16* __restrict__ Wpk) {
  const int f    = blockIdx.x;          // 0..511
  const int lane = threadIdx.x;         // 0..63
  const int kk  = f & 7;
  const int g16 = (f >> 3) & 15;
  const int p   = f >> 7;
  const float* W = (p == 0) ? Wq : (p == 1) ? Wk : (p == 2) ? Wv : Wo;
  const int lh = lane & 15, lq = lane >> 4;
  const int n  = g16 * 16 + lh;
  const int k0 = kk * 32 + lq * 8;
  const float4 s0 = *(const float4*)&W[n * 256 + k0];
  const float4 s1 = *(const float4*)&W[n * 256 + k0 + 4];
  bf16x8 r;
  r[0] = (__bf16)s0.x; r[1] = (__bf16)s0.y; r[2] = (__bf16)s0.z; r[3] = (__bf16)s0.w;
  r[4] = (__bf16)s1.x; r[5] = (__bf16)s1.y; r[6] = (__bf16)s1.z; r[7] = (__bf16)s1.w;
  *(bf16x8*)&Wpk[(size_t)f * 512 + lane * 8] = r;
}

// ---------- register W-frag preload: 16 frags = one proj slice for this wave ----------
// w[nf*8+kk] = frag (g16 = 2*wave+nf, kk); all indices compile-time -> registers.
__device__ __forceinline__ void loadW16(const __bf16* __restrict__ wbase, int lane,
                                        bf16x8 w[16]) {
  const __bf16* wl = wbase + lane * 8;
  #pragma unroll
  for (int f = 0; f < 16; ++f)
    w[f] = *(const bf16x8*)(wl + (size_t)f * 512);
}

// ---------- pure-compute projection: LDS A-frags x register W-frags ----------
__device__ __forceinline__ void projC(const __bf16* __restrict__ xs_, const bf16x8 w[16],
                                      int lh, int lq, f32x4 acc[4][2]) {
  const __bf16* ap = xs_ + lh * LDW + lq * 8;
  #pragma unroll
  for (int kk = 0; kk < 8; ++kk) {
    bf16x8 a0 = *(const bf16x8*)(ap +  0 * LDW + kk * 32);
    bf16x8 a1 = *(const bf16x8*)(ap + 16 * LDW + kk * 32);
    bf16x8 a2 = *(const bf16x8*)(ap + 32 * LDW + kk * 32);
    bf16x8 a3 = *(const bf16x8*)(ap + 48 * LDW + kk * 32);
    acc[0][0] = __builtin_amdgcn_mfma_f32_16x16x32_bf16(a0, w[kk],     acc[0][0], 0, 0, 0);
    acc[1][0] = __builtin_amdgcn_mfma_f32_16x16x32_bf16(a1, w[kk],     acc[1][0], 0, 0, 0);
    acc[2][0] = __builtin_amdgcn_mfma_f32_16x16x32_bf16(a2, w[kk],     acc[2][0], 0, 0, 0);
    acc[3][0] = __builtin_amdgcn_mfma_f32_16x16x32_bf16(a3, w[kk],     acc[3][0], 0, 0, 0);
    acc[0][1] = __builtin_amdgcn_mfma_f32_16x16x32_bf16(a0, w[8 + kk], acc[0][1], 0, 0, 0);
    acc[1][1] = __builtin_amdgcn_mfma_f32_16x16x32_bf16(a1, w[8 + kk], acc[1][1], 0, 0, 0);
    acc[2][1] = __builtin_amdgcn_mfma_f32_16x16x32_bf16(a2, w[8 + kk], acc[2][1], 0, 0, 0);
    acc[3][1] = __builtin_amdgcn_mfma_f32_16x16x32_bf16(a3, w[8 + kk], acc[3][1], 0, 0, 0);
  }
}

#define ZERO_ACC(acc)                                            \
  _Pragma("unroll")                                              \
  for (int mf_ = 0; mf_ < 4; ++mf_)                              \
    _Pragma("unroll")                                            \
    for (int nf_ = 0; nf_ < 2; ++nf_)                            \
      acc[mf_][nf_] = (f32x4){0.f, 0.f, 0.f, 0.f};

__device__ __forceinline__ void store_cd64(__bf16* __restrict__ buf, const f32x4 acc[4][2],
                                           const float* __restrict__ bias,
                                           int n0, int lh, int lq) {
  #pragma unroll
  for (int nf = 0; nf < 2; ++nf) {
    int col = n0 + nf * 16 + lh;
    float bb = bias[col];
    #pragma unroll
    for (int mf = 0; mf < 4; ++mf) {
      int r = mf * 16 + lq * 4;
      #pragma unroll
      for (int j = 0; j < 4; ++j)
        buf[(r + j) * LDW + col] = (__bf16)(acc[mf][nf][j] + bb);
    }
  }
}

__launch_bounds__(512, 2)
__global__ void fused_attn(const float* __restrict__ x, const __bf16* __restrict__ Wpk,
                           const float* __restrict__ bq, const float* __restrict__ bk,
                           const float* __restrict__ bv, const float* __restrict__ bo,
                           float* __restrict__ out) {
  __shared__ __bf16 xs[MROWS * LDW];    // x tile (live through V projection)
  __shared__ __bf16 qs[MROWS * LDW];    // Q, then V
  __shared__ __bf16 ksh[MROWS * LDW];   // K, then Y
  __shared__ float PL[MROWS * 16];

  const int tid  = threadIdx.x;          // 0..511
  const int lane = tid & 63;
  const int w    = tid >> 6;             // wave 0..7
  const int lh   = lane & 15;
  const int lq   = lane >> 4;
  const int n0   = w * 32;
  const int tok0 = blockIdx.x * MROWS;

  // ---- stage x tile: lane-contiguous float4 loads -> bf16 padded LDS ----
  const float4* xg = (const float4*)(x + (size_t)tok0 * 256);
  #pragma unroll
  for (int i = 0; i < 8; ++i) {
    int idx = i * 512 + tid;           // float4 id, 0..4095
    int row = idx >> 6;                // 64 float4 per row
    int c4  = idx & 63;
    float4 v = xg[idx];
    bf16x4 pk;
    pk[0] = (__bf16)v.x; pk[1] = (__bf16)v.y; pk[2] = (__bf16)v.z; pk[3] = (__bf16)v.w;
    *(bf16x4*)&xs[row * LDW + c4 * 4] = pk;
  }

  // per-(proj,wave) packed-weight base: frag_id = p*128 + (2w+nf)*8 + kk
  const __bf16* wqb = Wpk + (size_t)(0 * 128 + w * 16) * 512;
  const __bf16* wkb = Wpk + (size_t)(1 * 128 + w * 16) * 512;
  const __bf16* wvb = Wpk + (size_t)(2 * 128 + w * 16) * 512;
  const __bf16* wob = Wpk + (size_t)(3 * 128 + w * 16) * 512;

  // ---- preload Q and K weight slices into registers (loads overlap staging) ----
  bf16x8 wq[16], wk[16];
  loadW16(wqb, lane, wq);
  loadW16(wkb, lane, wk);
  __syncthreads();                       // x staged

  // ---- Q projection (pure LDS+MFMA; W already resident) ----
  {
    f32x4 acc[4][2];
    ZERO_ACC(acc);
    projC(xs, wq, lh, lq, acc);
    store_cd64(qs, acc, bq, n0, lh, lq);
  }
  // ---- K projection ----
  {
    f32x4 acc[4][2];
    ZERO_ACC(acc);
    projC(xs, wk, lh, lq, acc);
    store_cd64(ksh, acc, bk, n0, lh, lq);
  }

  // ---- preload V weight slice; its L2 latency hides under softmax ----
  bf16x8 wv[16];
  loadW16(wvb, lane, wv);
  __syncthreads();   // Q,K visible

  // ---- scores + softmax: 8 threads/token, all 64 lanes active ----
  // thread (m, h=sub&3, kh=sub>>2) computes partial dots over d in [kh*32, kh*32+32);
  // halves combined via shfl_xor lane^4 (same token, other kh).
  {
    const int m   = tid >> 3;            // 0..63
    const int sub = tid & 7;
    const int h   = sub & 3;
    const int kh  = sub >> 2;
    const int dof = kh * 32;
    float d0 = 0.f, d1 = 0.f, d2 = 0.f, d3 = 0.f;
    #pragma unroll
    for (int i = 0; i < 4; ++i) {
      bf16x8 qv = *(const bf16x8*)&qs[m * LDW + h * 64 + dof + i * 8];
      bf16x8 k0 = *(const bf16x8*)&ksh[m * LDW +   0 + dof + i * 8];
      bf16x8 k1 = *(const bf16x8*)&ksh[m * LDW +  64 + dof + i * 8];
      bf16x8 k2 = *(const bf16x8*)&ksh[m * LDW + 128 + dof + i * 8];
      bf16x8 k3 = *(const bf16x8*)&ksh[m * LDW + 192 + dof + i * 8];
      #pragma unroll
      for (int j = 0; j < 8; ++j) {
        float qf = (float)qv[j];
        d0 += qf * (float)k0[j];
        d1 += qf * (float)k1[j];
        d2 += qf * (float)k2[j];
        d3 += qf * (float)k3[j];
      }
    }
    d0 += __shfl_xor(d0, 4);
    d1 += __shfl_xor(d1, 4);
    d2 += __shfl_xor(d2, 4);
    d3 += __shfl_xor(d3, 4);
    d0 *= 0.125f; d1 *= 0.125f; d2 *= 0.125f; d3 *= 0.125f;  // 1/sqrt(64)
    float mx = fmaxf(fmaxf(d0, d1), fmaxf(d2, d3));
    float e0 = expf(d0 - mx), e1 = expf(d1 - mx), e2 = expf(d2 - mx), e3 = expf(d3 - mx);
    float inv = 1.0f / (e0 + e1 + e2 + e3);
    if (kh == 0) {
      float* pl = &PL[m * 16 + h * 4];
      pl[0] = e0 * inv; pl[1] = e1 * inv; pl[2] = e2 * inv; pl[3] = e3 * inv;
    }
  }
  __syncthreads();   // P visible; Q,K reads complete

  // ---- V projection (overwrites Q region; W resident since before softmax) ----
  {
    f32x4 acc[4][2];
    ZERO_ACC(acc);
    projC(xs, wv, lh, lq, acc);
    store_cd64(qs, acc, bv, n0, lh, lq);
  }

  // ---- preload O weight slice; latency hides under ymix ----
  bf16x8 wo[16];
  loadW16(wob, lane, wo);
  __syncthreads();   // V visible

  // ---- y-mix: y[m, h*64+d] = sum_g P[h][g] * v[m, g*64+d]; Y -> ksh ----
  {
    const int m   = tid >> 3;            // 0..63
    const int sub = tid & 7;
    const int h   = sub >> 1;
    const int c0  = (sub & 1) * 32;
    const float p0 = PL[m * 16 + h * 4 + 0];
    const float p1 = PL[m * 16 + h * 4 + 1];
    const float p2 = PL[m * 16 + h * 4 + 2];
    const float p3 = PL[m * 16 + h * 4 + 3];
    #pragma unroll
    for (int dd = 0; dd < 32; dd += 8) {
      int c = c0 + dd;
      bf16x8 v0 = *(const bf16x8*)&qs[m * LDW +   0 + c];
      bf16x8 v1 = *(const bf16x8*)&qs[m * LDW +  64 + c];
      bf16x8 v2 = *(const bf16x8*)&qs[m * LDW + 128 + c];
      bf16x8 v3 = *(const bf16x8*)&qs[m * LDW + 192 + c];
      bf16x8 yv;
      #pragma unroll
      for (int j = 0; j < 8; ++j) {
        float f = p0 * (float)v0[j] + p1 * (float)v1[j]
                + p2 * (float)v2[j] + p3 * (float)v3[j];
        yv[j] = (__bf16)f;
      }
      *(bf16x8*)&ksh[m * LDW + h * 64 + c] = yv;
    }
  }
  __syncthreads();   // Y visible

  // ---- output GEMM: out = Y @ Wo^T + bo (A from LDS Y in ksh) ----
  {
    f32x4 acc[4][2];
    ZERO_ACC(acc);
    projC(ksh, wo, lh, lq, acc);

    #pragma unroll
    for (int nf = 0; nf < 2; ++nf) {
      int col = n0 + nf * 16 + lh;
      float bb = bo[col];
      #pragma unroll
      for (int mf = 0; mf < 4; ++mf) {
        int rbase = tok0 + mf * 16 + lq * 4;
        #pragma unroll
        for (int j = 0; j < 4; ++j)
          out[(size_t)(rbase + j) * 256 + col] = acc[mf][nf][j] + bb;
      }
    }
  }
}

extern "C" void kernel_launch(void* const* d_in, const int* in_sizes, int n_in,
                              void* d_out, int out_size, void* d_ws, size_t ws_size,
                              hipStream_t stream) {
  const float* x  = (const float*)d_in[0];
  const float* Wq = (const float*)d_in[1];
  const float* bq = (const float*)d_in[2];
  const float* Wk = (const float*)d_in[3];
  const float* bk = (const float*)d_in[4];
  const float* Wv = (const float*)d_in[5];
  const float* bv = (const float*)d_in[6];
  const float* Wo = (const float*)d_in[7];
  const float* bo = (const float*)d_in[8];
  float* out = (float*)d_out;
  __bf16* Wpk = (__bf16*)d_ws;   // 512 frags x 1KB = 512 KB

  pack_wfrag<<<dim3(512), dim3(64), 0, stream>>>(Wq, Wk, Wv, Wo, Wpk);
  fused_attn<<<dim3(512), dim3(512), 0, stream>>>(x, Wpk, bq, bk, bv, bo, out);
}